// Round 1
// baseline (1958.421 us; speedup 1.0000x reference)
//
#include <hip/hip_runtime.h>
#include <hip/hip_fp16.h>
#include <math.h>

#define NROWS 65536
#define KCOLS 1024
#define GBLK  256
#define SINK_TOL 0.1
#define MAXIT 2000

__device__ __forceinline__ double wredd(double v){
#pragma unroll
  for (int m = 1; m < 64; m <<= 1) v += __shfl_xor(v, m);
  return v;
}
__device__ __forceinline__ float wredf(float v){
#pragma unroll
  for (int m = 1; m < 64; m <<= 1) v += __shfl_xor(v, m);
  return v;
}
__device__ __forceinline__ float wmaxf(float v){
#pragma unroll
  for (int m = 1; m < 64; m <<= 1) v = fmaxf(v, __shfl_xor(v, m));
  return v;
}

// Pass 1: f64 row-softmax of f32 logits -> fp16 PS (first 128MB of d_out),
// plus exact-ish f64 column sums (for the argsort + first alpha).
__global__ __launch_bounds__(256, 4) void pass1_kernel(
    const float* __restrict__ logits, __half* __restrict__ ps16,
    double* __restrict__ colsum)
{
  __shared__ double comb[2][1024];
  const int tid = threadIdx.x, lane = tid & 63, w = tid >> 6;   // 4 waves
  const size_t row0 = ((size_t)blockIdx.x * 4 + w) * 16;
  double cacc[16];
#pragma unroll
  for (int e = 0; e < 16; ++e) cacc[e] = 0.0;

  for (int rr = 0; rr < 16; ++rr) {
    const size_t n = row0 + rr;
    const float4* rp = (const float4*)(logits + n * KCOLS);
    float4 v0 = rp[4*lane+0], v1 = rp[4*lane+1], v2 = rp[4*lane+2], v3 = rp[4*lane+3];
    float xs[16] = {v0.x,v0.y,v0.z,v0.w, v1.x,v1.y,v1.z,v1.w,
                    v2.x,v2.y,v2.z,v2.w, v3.x,v3.y,v3.z,v3.w};
    float mx = xs[0];
#pragma unroll
    for (int e = 1; e < 16; ++e) mx = fmaxf(mx, xs[e]);
    mx = wmaxf(mx);
    double ev[16]; double ls = 0.0;
#pragma unroll
    for (int e = 0; e < 16; ++e) { ev[e] = exp((double)xs[e] - (double)mx); ls += ev[e]; }
    ls = wredd(ls);
    const double inv = 1.0 / ls;
    union { __half2 h2[8]; int4 i4[2]; } u;
#pragma unroll
    for (int q = 0; q < 8; ++q)
      u.h2[q] = __floats2half2_rn((float)(ev[2*q] * inv), (float)(ev[2*q+1] * inv));
    int4* op = (int4*)(ps16 + n * KCOLS);
    op[2*lane+0] = u.i4[0];
    op[2*lane+1] = u.i4[1];
#pragma unroll
    for (int e = 0; e < 16; ++e) cacc[e] += ev[e] * inv;
  }
  // combine 4 waves (transposed LDS layout: index e*64+lane -> column 16*lane+e)
  if (w < 2) {
#pragma unroll
    for (int e = 0; e < 16; ++e) comb[w][e*64+lane] = cacc[e];
  }
  __syncthreads();
  if (w >= 2) {
#pragma unroll
    for (int e = 0; e < 16; ++e) comb[w-2][e*64+lane] += cacc[e];
  }
  __syncthreads();
#pragma unroll
  for (int q = 0; q < 4; ++q) {
    const int c  = tid + 256*q;
    const int ix = (c & 15)*64 + (c >> 4);
    __hip_atomic_fetch_add(&colsum[c], comb[0][ix] + comb[1][ix],
                           __ATOMIC_RELAXED, __HIP_MEMORY_SCOPE_AGENT);
  }
}

// Bitonic argsort of 1024 f64 column sums, scatter-permute k_dist, build r and alpha_1.
__global__ __launch_bounds__(1024) void prep_kernel(
    const double* __restrict__ colsum, const float* __restrict__ kdist,
    double* __restrict__ rG, double* __restrict__ alphaG)
{
  __shared__ double key[1024];
  __shared__ int    sidx[1024];
  __shared__ double kperm[1024];
  __shared__ double red[1024];
  const int t = threadIdx.x;
  key[t]  = colsum[t];
  sidx[t] = t;
  __syncthreads();
  for (int k = 2; k <= 1024; k <<= 1) {
    for (int j = k >> 1; j > 0; j >>= 1) {
      const int p = t ^ j;
      if (p > t) {
        const bool up = ((t & k) == 0);
        double a = key[t], b = key[p];
        if ((a > b) == up) {
          key[t] = b; key[p] = a;
          int tmp = sidx[t]; sidx[t] = sidx[p]; sidx[p] = tmp;
        }
      }
      __syncthreads();
    }
  }
  // k_new[argsort[i]] = k_old[i]
  kperm[sidx[t]] = (double)kdist[t];
  __syncthreads();
  const double rr = 1.0 / kperm[t];
  red[t] = rr;
  __syncthreads();
  for (int s = 512; s > 0; s >>= 1) { if (t < s) red[t] += red[t+s]; __syncthreads(); }
  const double r = rr / red[0];
  rG[t] = r;
  alphaG[t] = r / (colsum[t] / (double)NROWS);   // alpha_1 = r / (beta0^T PS)
}

// Persistent Sinkhorn: one fused pass per iteration + device-wide barrier.
__global__ __launch_bounds__(1024, 4) void sink_kernel(
    const float* __restrict__ logits, const __half* ps16, float* out,
    const double* __restrict__ rG, double* alphaG, double* s_acc, double* errG,
    unsigned* genG, unsigned* cntG, unsigned* flagG)
{
  __shared__ double comb[4][1024];
  __shared__ double lalpha[1024];
  __shared__ double lerr[16];
  __shared__ unsigned llast, lstop;

  const int tid = threadIdx.x, lane = tid & 63, w = tid >> 6;   // 16 waves
  const int gw = blockIdx.x * 16 + w;
  const size_t row0 = (size_t)gw * 16;
  const double cN = 1.0 / (double)NROWS;
  double bprev = cN;              // beta_0 = 1/N (lane rr owns row row0+rr)
  double alo[16];
  int iter = 0;

  for (;;) {
    // stage alpha into LDS (transposed so each lane reads its 16 cols conflict-free)
    {
      double a = __hip_atomic_load(&alphaG[tid], __ATOMIC_RELAXED, __HIP_MEMORY_SCOPE_AGENT);
      lalpha[(tid & 15)*64 + (tid >> 4)] = a;
    }
    __syncthreads();
#pragma unroll
    for (int e = 0; e < 16; ++e) alo[e] = lalpha[e*64 + lane];

    double sacc[16];
#pragma unroll
    for (int e = 0; e < 16; ++e) sacc[e] = 0.0;
    double errloc = 0.0;
    const bool chk = (iter % 10) == 0;

    auto dorow = [&](int4 A, int4 B, int rr) {
      union { int4 v; __half2 h2[4]; } ua, ub;
      ua.v = A; ub.v = B;
      float f[16];
#pragma unroll
      for (int q = 0; q < 4; ++q) {
        float2 xa = __half22float2(ua.h2[q]);
        f[2*q]   = xa.x; f[2*q+1]   = xa.y;
        float2 xb = __half22float2(ub.h2[q]);
        f[8+2*q] = xb.x; f[8+2*q+1] = xb.y;
      }
      double tsum = 0.0;
#pragma unroll
      for (int e = 0; e < 16; ++e) tsum = fma((double)f[e], alo[e], tsum);
      tsum = wredd(tsum);
      const double bnew = cN / tsum;           // beta_{i+1}[n]
      if (lane == rr) {
        if (chk) errloc += fabs(bprev / bnew - 1.0);
        bprev = bnew;
      }
#pragma unroll
      for (int e = 0; e < 16; ++e) sacc[e] = fma(bnew, (double)f[e], sacc[e]);
    };

    for (int rr = 0; rr < 16; rr += 2) {
      const int4* rp0 = (const int4*)(ps16 + (row0 + rr    ) * KCOLS);
      const int4* rp1 = (const int4*)(ps16 + (row0 + rr + 1) * KCOLS);
      int4 A0 = rp0[2*lane], B0 = rp0[2*lane+1];
      int4 A1 = rp1[2*lane], B1 = rp1[2*lane+1];
      dorow(A0, B0, rr);
      dorow(A1, B1, rr + 1);
    }

    // combine 16 waves' column partials in LDS (4 slices, 4 rounds)
#pragma unroll
    for (int round = 0; round < 4; ++round) {
      if ((w >> 2) == round) {
        const int sl = w & 3;
        if (round == 0) {
#pragma unroll
          for (int e = 0; e < 16; ++e) comb[sl][e*64+lane] = sacc[e];
        } else {
#pragma unroll
          for (int e = 0; e < 16; ++e) comb[sl][e*64+lane] += sacc[e];
        }
      }
      __syncthreads();
    }
    if (chk) {
      errloc = wredd(errloc);
      if (lane == 0) lerr[w] = errloc;
    }
    __syncthreads();
    {
      const int c  = tid;
      const int ix = (c & 15)*64 + (c >> 4);
      const double tot = comb[0][ix] + comb[1][ix] + comb[2][ix] + comb[3][ix];
      __hip_atomic_fetch_add(&s_acc[c], tot, __ATOMIC_RELAXED, __HIP_MEMORY_SCOPE_AGENT);
    }
    if (chk && tid == 0) {
      double es = 0.0;
#pragma unroll
      for (int i = 0; i < 16; ++i) es += lerr[i];
      __hip_atomic_fetch_add(errG, es, __ATOMIC_RELAXED, __HIP_MEMORY_SCOPE_AGENT);
    }
    __syncthreads();

    // device-wide barrier; last-arriving block does phase B before releasing
    if (tid == 0) {
      __threadfence();
      unsigned old = __hip_atomic_fetch_add(cntG, 1u, __ATOMIC_ACQ_REL, __HIP_MEMORY_SCOPE_AGENT);
      llast = (old == (unsigned)(GBLK - 1)) ? 1u : 0u;
    }
    __syncthreads();
    if (llast) {
      __threadfence();
      const int c = tid;
      const double s = __hip_atomic_load(&s_acc[c], __ATOMIC_RELAXED, __HIP_MEMORY_SCOPE_AGENT);
      const double a = rG[c] / s;
      __hip_atomic_store(&alphaG[c], a, __ATOMIC_RELAXED, __HIP_MEMORY_SCOPE_AGENT);
      __hip_atomic_store(&s_acc[c], 0.0, __ATOMIC_RELAXED, __HIP_MEMORY_SCOPE_AGENT);
      if (tid == 0) {
        unsigned stop = 0u;
        if (chk) {
          const double ev = __hip_atomic_load(errG, __ATOMIC_RELAXED, __HIP_MEMORY_SCOPE_AGENT);
          if (ev <= SINK_TOL) stop = 1u;
          __hip_atomic_store(errG, 0.0, __ATOMIC_RELAXED, __HIP_MEMORY_SCOPE_AGENT);
        }
        if (iter >= MAXIT - 1) stop = 1u;
        __hip_atomic_store(flagG, stop, __ATOMIC_RELAXED, __HIP_MEMORY_SCOPE_AGENT);
        __hip_atomic_store(cntG, 0u, __ATOMIC_RELAXED, __HIP_MEMORY_SCOPE_AGENT);
      }
      __syncthreads();
      if (tid == 0) {
        __threadfence();
        __hip_atomic_store(genG, (unsigned)(iter + 1), __ATOMIC_RELEASE, __HIP_MEMORY_SCOPE_AGENT);
      }
    } else {
      if (tid == 0) {
        while (__hip_atomic_load(genG, __ATOMIC_ACQUIRE, __HIP_MEMORY_SCOPE_AGENT)
               < (unsigned)(iter + 1)) {
          __builtin_amdgcn_s_sleep(2);
        }
      }
      __syncthreads();
    }
    if (tid == 0) lstop = __hip_atomic_load(flagG, __ATOMIC_RELAXED, __HIP_MEMORY_SCOPE_AGENT);
    __syncthreads();
    ++iter;
    if (lstop) break;
  }

  // Final: out[n,k] = exp(l-m)*alpha / sum  (beta & softmax denom cancel; full f32 precision)
  float af[16];
#pragma unroll
  for (int e = 0; e < 16; ++e) af[e] = (float)alo[e];
  for (int rr = 0; rr < 16; ++rr) {
    const size_t n = row0 + rr;
    const float4* rp = (const float4*)(logits + n * KCOLS);
    float4 v0 = rp[4*lane+0], v1 = rp[4*lane+1], v2 = rp[4*lane+2], v3 = rp[4*lane+3];
    float xs[16] = {v0.x,v0.y,v0.z,v0.w, v1.x,v1.y,v1.z,v1.w,
                    v2.x,v2.y,v2.z,v2.w, v3.x,v3.y,v3.z,v3.w};
    float mx = xs[0];
#pragma unroll
    for (int e = 1; e < 16; ++e) mx = fmaxf(mx, xs[e]);
    mx = wmaxf(mx);
    float wv[16]; float ts = 0.f;
#pragma unroll
    for (int e = 0; e < 16; ++e) { wv[e] = expf(xs[e] - mx) * af[e]; ts += wv[e]; }
    ts = wredf(ts);
    const float inv = 1.0f / ts;
    float4* op = (float4*)(out + n * KCOLS);
    op[4*lane+0] = make_float4(wv[0]*inv,  wv[1]*inv,  wv[2]*inv,  wv[3]*inv);
    op[4*lane+1] = make_float4(wv[4]*inv,  wv[5]*inv,  wv[6]*inv,  wv[7]*inv);
    op[4*lane+2] = make_float4(wv[8]*inv,  wv[9]*inv,  wv[10]*inv, wv[11]*inv);
    op[4*lane+3] = make_float4(wv[12]*inv, wv[13]*inv, wv[14]*inv, wv[15]*inv);
  }
}

extern "C" void kernel_launch(void* const* d_in, const int* in_sizes, int n_in,
                              void* d_out, int out_size, void* d_ws, size_t ws_size,
                              hipStream_t stream)
{
  const float* logits = (const float*)d_in[0];
  const float* kdist  = (const float*)d_in[1];
  float*  out   = (float*)d_out;
  __half* ps16  = (__half*)d_out;            // fp16 PS lives in first 128MB of d_out
  const __half* ps16c = (const __half*)d_out;

  char* ws = (char*)d_ws;
  double*   colsum = (double*)(ws + 0);
  double*   rG     = (double*)(ws + 8192);
  const double* rGc = (const double*)(ws + 8192);
  double*   alphaG = (double*)(ws + 16384);
  double*   s_acc  = (double*)(ws + 24576);
  double*   errG   = (double*)(ws + 32768);
  unsigned* genG   = (unsigned*)(ws + 32768 + 64);
  unsigned* cntG   = (unsigned*)(ws + 32768 + 128);
  unsigned* flagG  = (unsigned*)(ws + 32768 + 192);

  hipMemsetAsync(d_ws, 0, 34 * 1024, stream);
  hipLaunchKernelGGL(pass1_kernel, dim3(1024), dim3(256), 0, stream, logits, ps16, colsum);
  hipLaunchKernelGGL(prep_kernel, dim3(1), dim3(1024), 0, stream,
                     (const double*)colsum, kdist, rG, alphaG);
  // 256 blocks x 1024 threads, <=128 VGPR (launch_bounds) and 40KB LDS:
  // every CU can host one block -> all 256 blocks are co-resident; custom
  // device-scope barrier inside handles the data-dependent while-loop.
  hipLaunchKernelGGL(sink_kernel, dim3(GBLK), dim3(1024), 0, stream,
                     logits, ps16c, out, rGc, alphaG, s_acc, errG, genG, cntG, flagG);
}

// Round 2
// 1530.706 us; speedup vs baseline: 1.2794x; 1.2794x over previous
//
#include <hip/hip_runtime.h>
#include <math.h>

#define NROWS 65536
#define KCOLS 1024
#define GBLK  256
#define SINK_TOL 0.1
#define MAXIT 2000

typedef float f32x2 __attribute__((ext_vector_type(2)));

__device__ __forceinline__ double wredd(double v){
#pragma unroll
  for (int m = 1; m < 64; m <<= 1) v += __shfl_xor(v, m);
  return v;
}
__device__ __forceinline__ float wredf(float v){
#pragma unroll
  for (int m = 1; m < 64; m <<= 1) v += __shfl_xor(v, m);
  return v;
}
__device__ __forceinline__ float wmaxf(float v){
#pragma unroll
  for (int m = 1; m < 64; m <<= 1) v = fmaxf(v, __shfl_xor(v, m));
  return v;
}

// Pass 1: f32 softmax terms, f64 column-sum accumulation (argsort needs ~1e-8;
// independent f32 term errors average to ~1e-9 vs adjacent-gap ~1e-6). No PS write.
__global__ __launch_bounds__(256, 4) void pass1_kernel(
    const float* __restrict__ logits, double* __restrict__ colsum)
{
  __shared__ double comb[2][1024];
  const int tid = threadIdx.x, lane = tid & 63, w = tid >> 6;   // 4 waves
  const size_t row0 = ((size_t)blockIdx.x * 4 + w) * 16;
  double cacc[16];
#pragma unroll
  for (int e = 0; e < 16; ++e) cacc[e] = 0.0;

  for (int rr = 0; rr < 16; ++rr) {
    const size_t n = row0 + rr;
    const float4* rp = (const float4*)(logits + n * KCOLS);
    float4 v0 = rp[4*lane+0], v1 = rp[4*lane+1], v2 = rp[4*lane+2], v3 = rp[4*lane+3];
    float xs[16] = {v0.x,v0.y,v0.z,v0.w, v1.x,v1.y,v1.z,v1.w,
                    v2.x,v2.y,v2.z,v2.w, v3.x,v3.y,v3.z,v3.w};
    float mx = xs[0];
#pragma unroll
    for (int e = 1; e < 16; ++e) mx = fmaxf(mx, xs[e]);
    mx = wmaxf(mx);
    float ev[16]; float ls = 0.f;
#pragma unroll
    for (int e = 0; e < 16; ++e) { ev[e] = expf(xs[e] - mx); ls += ev[e]; }
    ls = wredf(ls);
    const float inv = 1.0f / ls;
#pragma unroll
    for (int e = 0; e < 16; ++e) cacc[e] += (double)(ev[e] * inv);
  }
  if (w < 2) {
#pragma unroll
    for (int e = 0; e < 16; ++e) comb[w][e*64+lane] = cacc[e];
  }
  __syncthreads();
  if (w >= 2) {
#pragma unroll
    for (int e = 0; e < 16; ++e) comb[w-2][e*64+lane] += cacc[e];
  }
  __syncthreads();
#pragma unroll
  for (int q = 0; q < 4; ++q) {
    const int c  = tid + 256*q;
    const int ix = (c & 15)*64 + (c >> 4);
    __hip_atomic_fetch_add(&colsum[c], comb[0][ix] + comb[1][ix],
                           __ATOMIC_RELAXED, __HIP_MEMORY_SCOPE_AGENT);
  }
}

// Bitonic argsort of exact column sums, scatter-permute k_dist, build r (f64) and alpha_1 (f32).
__global__ __launch_bounds__(1024) void prep_kernel(
    const double* __restrict__ colsum, const float* __restrict__ kdist,
    double* __restrict__ rG, float* __restrict__ alphaF)
{
  __shared__ double key[1024];
  __shared__ int    sidx[1024];
  __shared__ double kperm[1024];
  __shared__ double red[1024];
  const int t = threadIdx.x;
  key[t]  = colsum[t];
  sidx[t] = t;
  __syncthreads();
  for (int k = 2; k <= 1024; k <<= 1) {
    for (int j = k >> 1; j > 0; j >>= 1) {
      const int p = t ^ j;
      if (p > t) {
        const bool up = ((t & k) == 0);
        double a = key[t], b = key[p];
        if ((a > b) == up) {
          key[t] = b; key[p] = a;
          int tmp = sidx[t]; sidx[t] = sidx[p]; sidx[p] = tmp;
        }
      }
      __syncthreads();
    }
  }
  kperm[sidx[t]] = (double)kdist[t];
  __syncthreads();
  const double rr = 1.0 / kperm[t];
  red[t] = rr;
  __syncthreads();
  for (int s = 512; s > 0; s >>= 1) { if (t < s) red[t] += red[t+s]; __syncthreads(); }
  const double r = rr / red[0];
  rG[t] = r;
  alphaF[t] = (float)(r / (colsum[t] / (double)NROWS));   // alpha_1
}

// Persistent Sinkhorn with the whole PS matrix resident in registers as fp8 e4m3.
// Per-row scale (stored = e^(x-m)*256): exactly transparent to the alpha/err trajectory.
__global__ __launch_bounds__(1024, 4) void sink_kernel(
    const float* __restrict__ logits, float* __restrict__ out,
    const double* __restrict__ rG, float* alphaF,
    double* s_accP, double* errG, unsigned* cntP, unsigned* cntF, unsigned* genRep)
{
  __shared__ float comb[16*1024];     // 64 KB: one slice per wave
  __shared__ float lalpha[1024];
  __shared__ float lerr[16];
  __shared__ unsigned lword;          // this block is phase-B owner
  __shared__ unsigned lstop_s;

  const int tid = threadIdx.x, lane = tid & 63, w = tid >> 6;   // 16 waves
  const int bid = blockIdx.x;
  const size_t row0 = ((size_t)bid * 16 + w) * 16;
  const float cNf = 1.0f / (float)NROWS;

  unsigned ps[16][4];                 // 64 VGPRs: 16 rows x 16 fp8 columns
  float bprev = 1.0f;

  // ---- build: f32 softmax -> fp8, per-row scale 256; beta0' = cN/(256*ls) ----
  for (int rr = 0; rr < 16; ++rr) {
    const float4* rp = (const float4*)(logits + (row0 + rr) * KCOLS);
    float4 v0 = rp[4*lane+0], v1 = rp[4*lane+1], v2 = rp[4*lane+2], v3 = rp[4*lane+3];
    float xs[16] = {v0.x,v0.y,v0.z,v0.w, v1.x,v1.y,v1.z,v1.w,
                    v2.x,v2.y,v2.z,v2.w, v3.x,v3.y,v3.z,v3.w};
    float mx = xs[0];
#pragma unroll
    for (int e = 1; e < 16; ++e) mx = fmaxf(mx, xs[e]);
    mx = wmaxf(mx);
    float ev[16]; float ls = 0.f;
#pragma unroll
    for (int e = 0; e < 16; ++e) { ev[e] = __expf(xs[e] - mx); ls += ev[e]; }
    ls = wredf(ls);
    if (lane == rr) bprev = cNf / (256.0f * ls);
#pragma unroll
    for (int q = 0; q < 4; ++q) {
      int u = 0;
      u = __builtin_amdgcn_cvt_pk_fp8_f32(ev[4*q+0]*256.0f, ev[4*q+1]*256.0f, u, false);
      u = __builtin_amdgcn_cvt_pk_fp8_f32(ev[4*q+2]*256.0f, ev[4*q+3]*256.0f, u, true);
      ps[rr][q] = (unsigned)u;
    }
  }

  f32x2 alo2[8], sacc2[8];
  int iter = 0;
  unsigned stopbit = 0;

  for (;;) {
    // stage alpha (f32) into LDS, transposed for conflict-free per-lane reads
    {
      float a = __hip_atomic_load(&alphaF[tid], __ATOMIC_RELAXED, __HIP_MEMORY_SCOPE_AGENT);
      lalpha[(tid & 15)*64 + (tid >> 4)] = a;
    }
    __syncthreads();
#pragma unroll
    for (int q = 0; q < 8; ++q) {
      alo2[q].x = lalpha[(2*q  )*64 + lane];
      alo2[q].y = lalpha[(2*q+1)*64 + lane];
    }
#pragma unroll
    for (int q = 0; q < 8; ++q) sacc2[q] = (f32x2){0.f, 0.f};
    float errloc = 0.f;
    const bool chk = (iter % 10) == 0;

#pragma unroll
    for (int rr = 0; rr < 16; ++rr) {
      f32x2 t2 = {0.f, 0.f};
#pragma unroll
      for (int q = 0; q < 4; ++q) {       // decode #1: dot with alpha
        f32x2 lo = __builtin_amdgcn_cvt_pk_f32_fp8((int)ps[rr][q], false);
        f32x2 hi = __builtin_amdgcn_cvt_pk_f32_fp8((int)ps[rr][q], true);
        t2 = t2 + lo * alo2[2*q] + hi * alo2[2*q+1];
      }
      float tsum = t2.x + t2.y;
      tsum = wredf(tsum);
      const float bnew = cNf * __builtin_amdgcn_rcpf(tsum);
      if (lane == rr) {
        if (chk) errloc += fabsf(bprev * tsum * (float)NROWS - 1.0f);  // = |bprev/bnew - 1|
        bprev = bnew;
      }
      const f32x2 b2 = {bnew, bnew};
#pragma unroll
      for (int q = 0; q < 4; ++q) {       // decode #2: column scatter (keeps VGPR <= 128)
        f32x2 lo = __builtin_amdgcn_cvt_pk_f32_fp8((int)ps[rr][q], false);
        f32x2 hi = __builtin_amdgcn_cvt_pk_f32_fp8((int)ps[rr][q], true);
        sacc2[2*q  ] = sacc2[2*q  ] + lo * b2;
        sacc2[2*q+1] = sacc2[2*q+1] + hi * b2;
      }
    }

    // one-shot 16-wave combine: write own slice (2-way bank alias = free),
    // read 64-consecutive (conflict-free), then 32-contention split atomics
#pragma unroll
    for (int e = 0; e < 16; ++e)
      comb[w*1024 + e*64 + lane] = sacc2[e >> 1][e & 1];
    if (chk) {
      errloc = wredf(errloc);
      if (lane == 0) lerr[w] = errloc;
    }
    __syncthreads();
    {
      float tot = 0.f;
#pragma unroll
      for (int ww = 0; ww < 16; ++ww) tot += comb[ww*1024 + tid];
      const int col = 16*(tid & 63) + (tid >> 6);
      __hip_atomic_fetch_add(&s_accP[(size_t)(bid & 7)*1024 + col], (double)tot,
                             __ATOMIC_RELAXED, __HIP_MEMORY_SCOPE_AGENT);
    }
    if (chk && tid == 0) {
      float es = 0.f;
#pragma unroll
      for (int i = 0; i < 16; ++i) es += lerr[i];
      __hip_atomic_fetch_add(errG, (double)es, __ATOMIC_RELAXED, __HIP_MEMORY_SCOPE_AGENT);
    }
    __syncthreads();

    // two-level arrival: 8 sub-counters (32 each) -> final counter (8)
    if (tid == 0) {
      __threadfence();
      unsigned lw = 0;
      unsigned old = __hip_atomic_fetch_add(&cntP[(bid & 7)*16], 1u,
                                            __ATOMIC_ACQ_REL, __HIP_MEMORY_SCOPE_AGENT);
      if (old == 31u) {
        unsigned oldF = __hip_atomic_fetch_add(cntF, 1u,
                                               __ATOMIC_ACQ_REL, __HIP_MEMORY_SCOPE_AGENT);
        lw = (oldF == 7u) ? 1u : 0u;
      }
      lword = lw;
    }
    __syncthreads();

    if (lword) {
      // -------- phase B (last block): alpha = r/s, reset, release with stop bit --------
      __threadfence();
      double s = 0.0;
#pragma unroll
      for (int p = 0; p < 8; ++p) {
        s += __hip_atomic_load(&s_accP[p*1024 + tid], __ATOMIC_RELAXED, __HIP_MEMORY_SCOPE_AGENT);
        __hip_atomic_store(&s_accP[p*1024 + tid], 0.0, __ATOMIC_RELAXED, __HIP_MEMORY_SCOPE_AGENT);
      }
      const float a = (float)(rG[tid] / s);
      __hip_atomic_store(&alphaF[tid], a, __ATOMIC_RELAXED, __HIP_MEMORY_SCOPE_AGENT);
      if (tid == 0) {
        unsigned stop = 0u;
        if (chk) {
          const double ev = __hip_atomic_load(errG, __ATOMIC_RELAXED, __HIP_MEMORY_SCOPE_AGENT);
          if (ev <= SINK_TOL) stop = 1u;
          __hip_atomic_store(errG, 0.0, __ATOMIC_RELAXED, __HIP_MEMORY_SCOPE_AGENT);
        }
        if (iter >= MAXIT - 1) stop = 1u;
#pragma unroll
        for (int p = 0; p < 8; ++p)
          __hip_atomic_store(&cntP[p*16], 0u, __ATOMIC_RELAXED, __HIP_MEMORY_SCOPE_AGENT);
        __hip_atomic_store(cntF, 0u, __ATOMIC_RELAXED, __HIP_MEMORY_SCOPE_AGENT);
        lstop_s = stop;
      }
      __syncthreads();
      if (tid < 16) {
        __threadfence();
        __hip_atomic_store(&genRep[tid*16],
                           (unsigned)(iter + 1) | (lstop_s << 31),
                           __ATOMIC_RELEASE, __HIP_MEMORY_SCOPE_AGENT);
      }
      stopbit = lstop_s;
    } else {
      if (tid == 0) {
        unsigned g;
        for (;;) {
          g = __hip_atomic_load(&genRep[(bid & 15)*16], __ATOMIC_ACQUIRE, __HIP_MEMORY_SCOPE_AGENT);
          if ((g & 0x7fffffffu) >= (unsigned)(iter + 1)) break;
          __builtin_amdgcn_s_sleep(2);
        }
        lstop_s = g >> 31;
      }
      __syncthreads();
      stopbit = lstop_s;
    }
    ++iter;
    if (stopbit) break;
  }

  // ---- final: out[n,k] = exp(l-m)*alpha_k / rowsum, full f32 from logits ----
  float af[16];
#pragma unroll
  for (int e = 0; e < 16; ++e) af[e] = alo2[e >> 1][e & 1];
  for (int rr = 0; rr < 16; ++rr) {
    const size_t n = row0 + rr;
    const float4* rp = (const float4*)(logits + n * KCOLS);
    float4 v0 = rp[4*lane+0], v1 = rp[4*lane+1], v2 = rp[4*lane+2], v3 = rp[4*lane+3];
    float xs[16] = {v0.x,v0.y,v0.z,v0.w, v1.x,v1.y,v1.z,v1.w,
                    v2.x,v2.y,v2.z,v2.w, v3.x,v3.y,v3.z,v3.w};
    float mx = xs[0];
#pragma unroll
    for (int e = 1; e < 16; ++e) mx = fmaxf(mx, xs[e]);
    mx = wmaxf(mx);
    float wv[16]; float ts = 0.f;
#pragma unroll
    for (int e = 0; e < 16; ++e) { wv[e] = expf(xs[e] - mx) * af[e]; ts += wv[e]; }
    ts = wredf(ts);
    const float inv = 1.0f / ts;
    float4* op = (float4*)(out + n * KCOLS);
    op[4*lane+0] = make_float4(wv[0]*inv,  wv[1]*inv,  wv[2]*inv,  wv[3]*inv);
    op[4*lane+1] = make_float4(wv[4]*inv,  wv[5]*inv,  wv[6]*inv,  wv[7]*inv);
    op[4*lane+2] = make_float4(wv[8]*inv,  wv[9]*inv,  wv[10]*inv, wv[11]*inv);
    op[4*lane+3] = make_float4(wv[12]*inv, wv[13]*inv, wv[14]*inv, wv[15]*inv);
  }
}

extern "C" void kernel_launch(void* const* d_in, const int* in_sizes, int n_in,
                              void* d_out, int out_size, void* d_ws, size_t ws_size,
                              hipStream_t stream)
{
  const float* logits = (const float*)d_in[0];
  const float* kdist  = (const float*)d_in[1];
  float* out = (float*)d_out;

  char* ws = (char*)d_ws;
  double*   colsum = (double*)(ws + 0);        // 8 KB
  double*   rG     = (double*)(ws + 8192);     // 8 KB
  float*    alphaF = (float*) (ws + 16384);    // 4 KB
  double*   s_accP = (double*)(ws + 20480);    // 8 x 1024 f64 = 64 KB
  double*   errG   = (double*)(ws + 86016);
  unsigned* cntP   = (unsigned*)(ws + 86080);  // 8 counters, 64B apart
  unsigned* cntF   = (unsigned*)(ws + 86592);
  unsigned* genRep = (unsigned*)(ws + 86656);  // 16 replicas, 64B apart

  hipMemsetAsync(d_ws, 0, 88 * 1024, stream);
  hipLaunchKernelGGL(pass1_kernel, dim3(1024), dim3(256), 0, stream, logits, colsum);
  hipLaunchKernelGGL(prep_kernel, dim3(1), dim3(1024), 0, stream,
                     (const double*)colsum, kdist, rG, alphaF);
  hipLaunchKernelGGL(sink_kernel, dim3(GBLK), dim3(1024), 0, stream,
                     logits, out, (const double*)rG, alphaF, s_accP, errG, cntP, cntF, genRep);
}

// Round 3
// 731.144 us; speedup vs baseline: 2.6786x; 2.0936x over previous
//
#include <hip/hip_runtime.h>
#include <math.h>

#define NROWS 65536
#define KCOLS 1024
#define GBLK  256
#define SINK_TOL 0.1
#define MAXIT 2000

typedef float f32x2 __attribute__((ext_vector_type(2)));

__device__ __forceinline__ double wredd(double v){
#pragma unroll
  for (int m = 1; m < 64; m <<= 1) v += __shfl_xor(v, m);
  return v;
}
__device__ __forceinline__ float wredf(float v){
#pragma unroll
  for (int m = 1; m < 64; m <<= 1) v += __shfl_xor(v, m);
  return v;
}
__device__ __forceinline__ float wmaxf(float v){
#pragma unroll
  for (int m = 1; m < 64; m <<= 1) v = fmaxf(v, __shfl_xor(v, m));
  return v;
}

// Pass 1: f32 softmax terms, f64 per-thread + LDS + atomic accumulation of column
// sums. Argsort adjacent gaps ~1e-6 absolute; this path's error ~3e-8. Unchanged.
__global__ __launch_bounds__(256, 4) void pass1_kernel(
    const float* __restrict__ logits, double* __restrict__ colsum)
{
  __shared__ double comb[2][1024];
  const int tid = threadIdx.x, lane = tid & 63, w = tid >> 6;   // 4 waves
  const size_t row0 = ((size_t)blockIdx.x * 4 + w) * 16;
  double cacc[16];
#pragma unroll
  for (int e = 0; e < 16; ++e) cacc[e] = 0.0;

  for (int rr = 0; rr < 16; ++rr) {
    const size_t n = row0 + rr;
    const float4* rp = (const float4*)(logits + n * KCOLS);
    float4 v0 = rp[4*lane+0], v1 = rp[4*lane+1], v2 = rp[4*lane+2], v3 = rp[4*lane+3];
    float xs[16] = {v0.x,v0.y,v0.z,v0.w, v1.x,v1.y,v1.z,v1.w,
                    v2.x,v2.y,v2.z,v2.w, v3.x,v3.y,v3.z,v3.w};
    float mx = xs[0];
#pragma unroll
    for (int e = 1; e < 16; ++e) mx = fmaxf(mx, xs[e]);
    mx = wmaxf(mx);
    float ev[16]; float ls = 0.f;
#pragma unroll
    for (int e = 0; e < 16; ++e) { ev[e] = expf(xs[e] - mx); ls += ev[e]; }
    ls = wredf(ls);
    const float inv = 1.0f / ls;
#pragma unroll
    for (int e = 0; e < 16; ++e) cacc[e] += (double)(ev[e] * inv);
  }
  if (w < 2) {
#pragma unroll
    for (int e = 0; e < 16; ++e) comb[w][e*64+lane] = cacc[e];
  }
  __syncthreads();
  if (w >= 2) {
#pragma unroll
    for (int e = 0; e < 16; ++e) comb[w-2][e*64+lane] += cacc[e];
  }
  __syncthreads();
#pragma unroll
  for (int q = 0; q < 4; ++q) {
    const int c  = tid + 256*q;
    const int ix = (c & 15)*64 + (c >> 4);
    __hip_atomic_fetch_add(&colsum[c], comb[0][ix] + comb[1][ix],
                           __ATOMIC_RELAXED, __HIP_MEMORY_SCOPE_AGENT);
  }
}

// Persistent Sinkhorn. fp8 PS in registers; per-block redundant argsort; flat
// symmetric barrier: monotone two-level counters + 4-parity payload buffers with
// lag-2 zeroing; every block computes alpha locally (no phase-B owner chain).
__global__ __launch_bounds__(1024, 4) void sink_kernel(
    const float* __restrict__ logits, const float* __restrict__ kdist,
    float* __restrict__ out, const double* __restrict__ colsum,
    float* sacc4, float* errF4, unsigned* cntS, unsigned* cntM)
{
  __shared__ __align__(16) char sraw[65536];   // comb (64KB) / sort arrays (28KB)
  float*  comb   = (float*)sraw;
  double* skey   = (double*)sraw;              // 8 KB
  int*    ssidx  = (int*)(sraw + 8192);        // 4 KB
  double* skperm = (double*)(sraw + 12288);    // 8 KB
  double* sred   = (double*)(sraw + 20480);    // 8 KB
  __shared__ float lalpha[1024];
  __shared__ float lerr[16];
  __shared__ float lerrG;

  const int tid = threadIdx.x, lane = tid & 63, w = tid >> 6;   // 16 waves
  const int bid = blockIdx.x;
  const size_t row0 = ((size_t)bid * 16 + w) * 16;
  const float cNf = 1.0f / (float)NROWS;

  unsigned ps[16][4];                 // 64 VGPRs: 16 rows x 16 fp8 columns
  float bprev = 1.0f;

  // ---- build: f32 softmax -> fp8 with per-row scale 256 (Sinkhorn-invariant) ----
  for (int rr = 0; rr < 16; ++rr) {
    const float4* rp = (const float4*)(logits + (row0 + rr) * KCOLS);
    float4 v0 = rp[4*lane+0], v1 = rp[4*lane+1], v2 = rp[4*lane+2], v3 = rp[4*lane+3];
    float xs[16] = {v0.x,v0.y,v0.z,v0.w, v1.x,v1.y,v1.z,v1.w,
                    v2.x,v2.y,v2.z,v2.w, v3.x,v3.y,v3.z,v3.w};
    float mx = xs[0];
#pragma unroll
    for (int e = 1; e < 16; ++e) mx = fmaxf(mx, xs[e]);
    mx = wmaxf(mx);
    float ev[16]; float ls = 0.f;
#pragma unroll
    for (int e = 0; e < 16; ++e) { ev[e] = __expf(xs[e] - mx); ls += ev[e]; }
    ls = wredf(ls);
    if (lane == rr) bprev = cNf / (256.0f * ls);   // beta0' in the row-scaled system
#pragma unroll
    for (int q = 0; q < 4; ++q) {
      int u = 0;
      u = __builtin_amdgcn_cvt_pk_fp8_f32(ev[4*q+0]*256.0f, ev[4*q+1]*256.0f, u, false);
      u = __builtin_amdgcn_cvt_pk_fp8_f32(ev[4*q+2]*256.0f, ev[4*q+3]*256.0f, u, true);
      ps[rr][q] = (unsigned)u;
    }
  }

  // ---- redundant per-block bitonic argsort + r + alpha_1 (deterministic) ----
  float rF;
  {
    const int t = tid;
    const double cs = colsum[t];
    skey[t] = cs; ssidx[t] = t;
    __syncthreads();
    for (int k = 2; k <= 1024; k <<= 1) {
      for (int j = k >> 1; j > 0; j >>= 1) {
        const int pp = t ^ j;
        if (pp > t) {
          const bool up = ((t & k) == 0);
          double a = skey[t], b = skey[pp];
          if ((a > b) == up) {
            skey[t] = b; skey[pp] = a;
            int tm = ssidx[t]; ssidx[t] = ssidx[pp]; ssidx[pp] = tm;
          }
        }
        __syncthreads();
      }
    }
    skperm[ssidx[t]] = (double)kdist[t];
    __syncthreads();
    const double rr_d = 1.0 / skperm[t];
    sred[t] = rr_d;
    __syncthreads();
    for (int s2 = 512; s2 > 0; s2 >>= 1) { if (t < s2) sred[t] += sred[t+s2]; __syncthreads(); }
    const double r = rr_d / sred[0];
    rF = (float)r;                                    // thread t owns column t's r
    const float a1 = (float)(r / (cs / (double)NROWS));
    lalpha[(t & 15)*64 + (t >> 4)] = a1;              // transposed store
    __syncthreads();
  }

  f32x2 alo2[8], sacc2[8];
  int iter = 0;

  for (;;) {
    const int p = iter & 3;
    const unsigned genu = (unsigned)(iter >> 2) + 1u;

    // lag-2 zeroing of rotating buffers (ordered by the arrival release chain)
    {
      const int pz = (iter + 2) & 3;
      if (tid < 32)
        __hip_atomic_store(&sacc4[pz*8192 + bid*32 + tid], 0.f,
                           __ATOMIC_RELAXED, __HIP_MEMORY_SCOPE_AGENT);
      if (bid == 0 && tid == 32)
        __hip_atomic_store(&errF4[pz*16], 0.f,
                           __ATOMIC_RELAXED, __HIP_MEMORY_SCOPE_AGENT);
    }

    // load alpha fragments (conflict-free transposed reads)
#pragma unroll
    for (int q = 0; q < 8; ++q) {
      alo2[q].x = lalpha[(2*q  )*64 + lane];
      alo2[q].y = lalpha[(2*q+1)*64 + lane];
    }
#pragma unroll
    for (int q = 0; q < 8; ++q) sacc2[q] = (f32x2){0.f, 0.f};
    float errloc = 0.f;
    const bool chk = (iter % 10) == 0;

#pragma unroll
    for (int rr = 0; rr < 16; ++rr) {
      f32x2 t2 = {0.f, 0.f};
#pragma unroll
      for (int q = 0; q < 4; ++q) {       // decode #1: dot with alpha
        f32x2 lo = __builtin_amdgcn_cvt_pk_f32_fp8((int)ps[rr][q], false);
        f32x2 hi = __builtin_amdgcn_cvt_pk_f32_fp8((int)ps[rr][q], true);
        t2 = t2 + lo * alo2[2*q] + hi * alo2[2*q+1];
      }
      float tsum = t2.x + t2.y;
      tsum = wredf(tsum);
      const float bnew = cNf * __builtin_amdgcn_rcpf(tsum);
      if (lane == rr) {
        if (chk) errloc += fabsf(bprev * tsum * (float)NROWS - 1.0f);  // |bprev/bnew-1|
        bprev = bnew;
      }
      const f32x2 b2 = {bnew, bnew};
#pragma unroll
      for (int q = 0; q < 4; ++q) {       // decode #2: column scatter
        f32x2 lo = __builtin_amdgcn_cvt_pk_f32_fp8((int)ps[rr][q], false);
        f32x2 hi = __builtin_amdgcn_cvt_pk_f32_fp8((int)ps[rr][q], true);
        sacc2[2*q  ] = sacc2[2*q  ] + lo * b2;
        sacc2[2*q+1] = sacc2[2*q+1] + hi * b2;
      }
    }

    // 16-wave LDS combine + 8-way-partitioned f32 atomic column adds
#pragma unroll
    for (int e = 0; e < 16; ++e)
      comb[w*1024 + e*64 + lane] = sacc2[e >> 1][e & 1];
    if (chk) {
      errloc = wredf(errloc);
      if (lane == 0) lerr[w] = errloc;
    }
    __syncthreads();
    {
      float tot = 0.f;
#pragma unroll
      for (int ww = 0; ww < 16; ++ww) tot += comb[ww*1024 + tid];
      const int col = 16*(tid & 63) + (tid >> 6);
      __hip_atomic_fetch_add(&sacc4[p*8192 + (bid & 7)*1024 + col], tot,
                             __ATOMIC_RELAXED, __HIP_MEMORY_SCOPE_AGENT);
    }
    if (chk && tid == 0) {
      float es = 0.f;
#pragma unroll
      for (int i = 0; i < 16; ++i) es += lerr[i];
      __hip_atomic_fetch_add(&errF4[p*16], es,
                             __ATOMIC_RELAXED, __HIP_MEMORY_SCOPE_AGENT);
    }
    __syncthreads();   // drains all this block's atomics before the arrival release

    // flat symmetric barrier: two-level monotone counters, everyone polls master
    if (tid == 0) {
      __threadfence();
      unsigned old = __hip_atomic_fetch_add(&cntS[(p*8 + (bid & 7))*16], 1u,
                                            __ATOMIC_ACQ_REL, __HIP_MEMORY_SCOPE_AGENT);
      if (old == 32u*genu - 1u)
        __hip_atomic_fetch_add(&cntM[p*16], 1u,
                               __ATOMIC_ACQ_REL, __HIP_MEMORY_SCOPE_AGENT);
      while (__hip_atomic_load(&cntM[p*16], __ATOMIC_ACQUIRE, __HIP_MEMORY_SCOPE_AGENT)
             < 8u*genu) {
        __builtin_amdgcn_s_sleep(1);
      }
      if (chk)
        lerrG = __hip_atomic_load(&errF4[p*16], __ATOMIC_RELAXED, __HIP_MEMORY_SCOPE_AGENT);
    }
    __syncthreads();

    bool stop = (iter >= MAXIT - 1);
    if (chk && lerrG <= (float)SINK_TOL) stop = true;
    if (stop) break;                    // alo2 = alpha_{i+1}, matching reference exit

    // every block computes alpha_{i+2} locally
    {
      float s = 0.f;
#pragma unroll
      for (int part = 0; part < 8; ++part)
        s += __hip_atomic_load(&sacc4[p*8192 + part*1024 + tid],
                               __ATOMIC_RELAXED, __HIP_MEMORY_SCOPE_AGENT);
      const float a = rF / s;
      lalpha[(tid & 15)*64 + (tid >> 4)] = a;
    }
    __syncthreads();
    ++iter;
  }

  // ---- final: out[n,k] = exp(l-m)*alpha_k / rowsum, full f32 from logits ----
  float af[16];
#pragma unroll
  for (int e = 0; e < 16; ++e) af[e] = alo2[e >> 1][e & 1];
  for (int rr = 0; rr < 16; ++rr) {
    const size_t n = row0 + rr;
    const float4* rp = (const float4*)(logits + n * KCOLS);
    float4 v0 = rp[4*lane+0], v1 = rp[4*lane+1], v2 = rp[4*lane+2], v3 = rp[4*lane+3];
    float xs[16] = {v0.x,v0.y,v0.z,v0.w, v1.x,v1.y,v1.z,v1.w,
                    v2.x,v2.y,v2.z,v2.w, v3.x,v3.y,v3.z,v3.w};
    float mx = xs[0];
#pragma unroll
    for (int e = 1; e < 16; ++e) mx = fmaxf(mx, xs[e]);
    mx = wmaxf(mx);
    float wv[16]; float ts = 0.f;
#pragma unroll
    for (int e = 0; e < 16; ++e) { wv[e] = expf(xs[e] - mx) * af[e]; ts += wv[e]; }
    ts = wredf(ts);
    const float inv = 1.0f / ts;
    float4* op = (float4*)(out + n * KCOLS);
    op[4*lane+0] = make_float4(wv[0]*inv,  wv[1]*inv,  wv[2]*inv,  wv[3]*inv);
    op[4*lane+1] = make_float4(wv[4]*inv,  wv[5]*inv,  wv[6]*inv,  wv[7]*inv);
    op[4*lane+2] = make_float4(wv[8]*inv,  wv[9]*inv,  wv[10]*inv, wv[11]*inv);
    op[4*lane+3] = make_float4(wv[12]*inv, wv[13]*inv, wv[14]*inv, wv[15]*inv);
  }
}

extern "C" void kernel_launch(void* const* d_in, const int* in_sizes, int n_in,
                              void* d_out, int out_size, void* d_ws, size_t ws_size,
                              hipStream_t stream)
{
  const float* logits = (const float*)d_in[0];
  const float* kdist  = (const float*)d_in[1];
  float* out = (float*)d_out;

  char* ws = (char*)d_ws;
  double*   colsum = (double*)(ws + 0);          // 8 KB
  float*    sacc4  = (float*) (ws + 8192);       // 4 x 8 x 1024 f32 = 128 KB
  float*    errF4  = (float*) (ws + 139264);     // 4 slots, 64 B apart
  unsigned* cntS   = (unsigned*)(ws + 139520);   // 4 x 8 counters, 64 B apart
  unsigned* cntM   = (unsigned*)(ws + 141568);   // 4 counters, 64 B apart

  hipMemsetAsync(d_ws, 0, 144 * 1024, stream);
  hipLaunchKernelGGL(pass1_kernel, dim3(1024), dim3(256), 0, stream, logits, colsum);
  // 256 blocks x 1024 threads, VGPR<=128 (launch_bounds), ~70KB LDS:
  // one block per CU, all co-resident; in-kernel device barrier per iteration.
  hipLaunchKernelGGL(sink_kernel, dim3(GBLK), dim3(1024), 0, stream,
                     logits, kdist, out, (const double*)colsum, sacc4, errF4, cntS, cntM);
}